// Round 2
// baseline (6320.355 us; speedup 1.0000x reference)
//
#include <hip/hip_runtime.h>
#include <math.h>

// FrameTransformer fp32 baseline (v2: LDS<64KB in attention, ws<=26MB).
// Layout everywhere: (b=2, c=2, F, W=512), w contiguous; bc = b*2+c.
// GEMM: Y[bc][m][n] = sum_k pw[c][m][k] * B[bc][k][n]  (N=512 always)

__device__ __forceinline__ float4 ld4(const float* p){ return *(const float4*)p; }
__device__ __forceinline__ void st4(float* p, float4 v){ *(float4*)p = v; }
__device__ __forceinline__ float4 f4fma2(float a, float4 x, float b, float4 y){
  float4 r; r.x=a*x.x+b*y.x; r.y=a*x.y+b*y.y; r.z=a*x.z+b*y.z; r.w=a*x.w+b*y.w; return r;
}
__device__ __forceinline__ float4 f4add(float4 a, float4 b){
  float4 r; r.x=a.x+b.x; r.y=a.y+b.y; r.z=a.z+b.z; r.w=a.w+b.w; return r;
}
__device__ __forceinline__ float4 f4sqrelu(float4 a){
  float4 r;
  r.x = a.x>0.f ? a.x*a.x : 0.f; r.y = a.y>0.f ? a.y*a.y : 0.f;
  r.z = a.z>0.f ? a.z*a.z : 0.f; r.w = a.w>0.f ? a.w*a.w : 0.f;
  return r;
}

// ---------------- rope table: cos/sin[w][j], j=0..31 ----------------
__global__ __launch_bounds__(256) void rope_tab_k(float* __restrict__ cosT, float* __restrict__ sinT){
  int idx = blockIdx.x*256 + threadIdx.x;   // 512*32
  int w = idx >> 5, j = idx & 31;
  float th = (float)w * powf(10000.f, -(float)(2*j)/64.f);
  cosT[idx] = cosf(th);
  sinT[idx] = sinf(th);
}

// ---------------- frame-norm stats: mu/rs per (bc, w) ----------------
__global__ __launch_bounds__(256) void stats_k(const float* __restrict__ E,
                                               float* __restrict__ MU, float* __restrict__ RS){
  int w0 = blockIdx.x << 3;          // 64 w-tiles of 8
  int bc = blockIdx.y;
  int wl = threadIdx.x & 7, fg = threadIdx.x >> 3;  // 8 w x 32 f-groups
  const float* Ep = E + (size_t)bc*262144 + w0 + wl;
  float s = 0.f, q = 0.f;
  for (int f = fg; f < 512; f += 32){ float v = Ep[(size_t)f << 9]; s += v; q += v*v; }
  __shared__ float sS[256], sQ[256];
  sS[threadIdx.x] = s; sQ[threadIdx.x] = q;
  __syncthreads();
  if (threadIdx.x < 8){
    float S = 0.f, Q = 0.f;
    #pragma unroll
    for (int i = 0; i < 32; i++){ S += sS[i*8 + threadIdx.x]; Q += sQ[i*8 + threadIdx.x]; }
    float mu = S * (1.f/512.f);
    float var = Q * (1.f/512.f) - mu*mu;
    MU[bc*512 + w0 + threadIdx.x] = mu;
    RS[bc*512 + w0 + threadIdx.x] = rsqrtf(var + 1e-5f);
  }
}

// ---------------- GEMM ----------------
// EPI: 0 none, 1 sq_relu. ACC: += into Y. NORM: apply frame-norm to B while staging.
template<int EPI, bool ACC, bool NORM>
__global__ __launch_bounds__(256) void gemm_k(
    const float* __restrict__ A_, const float* __restrict__ B_, float* __restrict__ Y_,
    int M, int K,
    const float* __restrict__ MU, const float* __restrict__ RS,
    const float* __restrict__ G, const float* __restrict__ Bt)
{
  const int bc = blockIdx.z, c = bc & 1;
  const float* A = A_ + (size_t)c * M * K;
  const float* B = B_ + (size_t)bc * K * 512;
  float* Y = Y_ + (size_t)bc * M * 512;
  const int n0 = blockIdx.x << 6, m0 = blockIdx.y << 6;
  const int t = threadIdx.x;
  const int tx = t & 15, ty = t >> 4;
  __shared__ float As[16][68];
  __shared__ float Bs[16][68];
  float acc[4][4] = {};
  float mu = 0.f, rs = 0.f;
  if (NORM){ int n = n0 + (t & 63); mu = MU[bc*512 + n]; rs = RS[bc*512 + n]; }
  for (int k0 = 0; k0 < K; k0 += 16){
    __syncthreads();
    #pragma unroll
    for (int i = 0; i < 4; i++){
      int m = (t >> 4) + (i << 4);
      As[t & 15][m] = A[(size_t)(m0 + m)*K + (k0 + (t & 15))];
    }
    #pragma unroll
    for (int i = 0; i < 4; i++){
      int k = (t >> 6) + (i << 2);
      float v = B[(size_t)(k0 + k)*512 + (n0 + (t & 63))];
      if (NORM) v = (v - mu) * rs * G[c*512 + k0 + k] + Bt[c*512 + k0 + k];
      Bs[k][t & 63] = v;
    }
    __syncthreads();
    #pragma unroll
    for (int kk = 0; kk < 16; kk++){
      const float4 a = *(const float4*)&As[kk][ty << 2];
      const float4 b = *(const float4*)&Bs[kk][tx << 2];
      acc[0][0] += a.x*b.x; acc[0][1] += a.x*b.y; acc[0][2] += a.x*b.z; acc[0][3] += a.x*b.w;
      acc[1][0] += a.y*b.x; acc[1][1] += a.y*b.y; acc[1][2] += a.y*b.z; acc[1][3] += a.y*b.w;
      acc[2][0] += a.z*b.x; acc[2][1] += a.z*b.y; acc[2][2] += a.z*b.z; acc[2][3] += a.z*b.w;
      acc[3][0] += a.w*b.x; acc[3][1] += a.w*b.y; acc[3][2] += a.w*b.z; acc[3][3] += a.w*b.w;
    }
  }
  #pragma unroll
  for (int i = 0; i < 4; i++){
    int m = m0 + (ty << 2) + i;
    float4 r; r.x = acc[i][0]; r.y = acc[i][1]; r.z = acc[i][2]; r.w = acc[i][3];
    if (EPI == 1) r = f4sqrelu(r);
    float* dst = &Y[(size_t)m*512 + n0 + (tx << 2)];
    if (ACC) r = f4add(r, ld4(dst));
    st4(dst, r);
  }
}

// ---------------- channel mix (dw) ----------------
// MODE: 0 none, 1 sq_relu, 2 add Z
template<int MODE>
__global__ __launch_bounds__(256) void dwmix_k(
    const float* __restrict__ T, const float* __restrict__ dwp,
    const float* __restrict__ Z, float* __restrict__ O, int F)
{
  int idx = blockIdx.x*256 + threadIdx.x;
  int perb = F << 7;                 // F * 128 float4-groups
  int b = idx / perb; int rem = idx - b*perb;
  int f = rem >> 7; int w = (rem & 127) << 2;
  size_t i0 = ((size_t)(b*2 + 0)*F + f)*512 + w;
  size_t i1 = i0 + (size_t)F*512;
  float4 t0 = ld4(T + i0), t1 = ld4(T + i1);
  float d00 = dwp[0], d01 = dwp[1], d10 = dwp[2], d11 = dwp[3];
  float4 o0 = f4fma2(d00, t0, d01, t1);
  float4 o1 = f4fma2(d10, t0, d11, t1);
  if (MODE == 1){ o0 = f4sqrelu(o0); o1 = f4sqrelu(o1); }
  if (MODE == 2){ o0 = f4add(o0, ld4(Z + i0)); o1 = f4add(o1, ld4(Z + i1)); }
  st4(O + i0, o0);
  st4(O + i1, o1);
}

// ---------------- channel mix + RoPE (for q,k), F=512 ----------------
__global__ __launch_bounds__(256) void dwmix_rope_k(
    const float* __restrict__ T, const float* __restrict__ dwp, float* __restrict__ O,
    const float* __restrict__ cosT, const float* __restrict__ sinT)
{
  int idx = blockIdx.x*256 + threadIdx.x;   // 2 * 256 * 128
  int b = idx >> 15; int rem = idx & 32767;
  int fp = rem >> 7; int w = (rem & 127) << 2;
  int f = fp << 1;
  size_t i0 = ((size_t)(b*2 + 0)*512 + f)*512 + w;   // c=0, even row f
  size_t i1 = i0 + 262144;                           // c=1
  float4 e0 = ld4(T + i0), g0 = ld4(T + i0 + 512);
  float4 e1 = ld4(T + i1), g1 = ld4(T + i1 + 512);
  float d00 = dwp[0], d01 = dwp[1], d10 = dwp[2], d11 = dwp[3];
  float4 me0 = f4fma2(d00, e0, d01, e1);   // mixed even feature, d=0
  float4 mo0 = f4fma2(d00, g0, d01, g1);   // mixed odd  feature, d=0
  float4 me1 = f4fma2(d10, e0, d11, e1);
  float4 mo1 = f4fma2(d10, g0, d11, g1);
  int j = (f & 63) >> 1;
  const float* cp = cosT + (size_t)w*32 + j;
  const float* sp = sinT + (size_t)w*32 + j;
  float c0 = cp[0], c1 = cp[32], c2 = cp[64], c3 = cp[96];
  float s0 = sp[0], s1 = sp[32], s2 = sp[64], s3 = sp[96];
  float4 re0, ro0, re1, ro1;
  re0.x = me0.x*c0 - mo0.x*s0;  ro0.x = mo0.x*c0 + me0.x*s0;
  re0.y = me0.y*c1 - mo0.y*s1;  ro0.y = mo0.y*c1 + me0.y*s1;
  re0.z = me0.z*c2 - mo0.z*s2;  ro0.z = mo0.z*c2 + me0.z*s2;
  re0.w = me0.w*c3 - mo0.w*s3;  ro0.w = mo0.w*c3 + me0.w*s3;
  re1.x = me1.x*c0 - mo1.x*s0;  ro1.x = mo1.x*c0 + me1.x*s0;
  re1.y = me1.y*c1 - mo1.y*s1;  ro1.y = mo1.y*c1 + me1.y*s1;
  re1.z = me1.z*c2 - mo1.z*s2;  ro1.z = mo1.z*c2 + me1.z*s2;
  re1.w = me1.w*c3 - mo1.w*s3;  ro1.w = mo1.w*c3 + me1.w*s3;
  st4(O + i0, re0); st4(O + i0 + 512, ro0);
  st4(O + i1, re1); st4(O + i1 + 512, ro1);
}

// ---------------- fused attention ----------------
// grid (8 q-tiles, 8 heads, 4 bc); block 256 = 4 waves. K-tile = 32.
// q/k/v layout (bc, f=h*64+d, w). Online softmax over 16 k-tiles.
// LDS: 17408+8448+8320+9216+768 = 44160 B (<64KB).
__global__ __launch_bounds__(256) void attn_k(
    const float* __restrict__ Q, const float* __restrict__ K,
    const float* __restrict__ V, float* __restrict__ O)
{
  const int q0 = blockIdx.x << 6;
  const int h  = blockIdx.y;
  const int bc = blockIdx.z;
  const size_t hb = ((size_t)bc*512 + h*64)*512;
  const float* Qp = Q + hb;
  const float* Kp = K + hb;
  const float* Vp = V + hb;
  float*       Op = O + hb;
  __shared__ float Qt[64][68];   // Qt[d][q]  (reused for output staging)
  __shared__ float Kt[64][33];   // Kt[d][k']
  __shared__ float Vt[32][65];   // Vt[k'][d]
  __shared__ float St[64][36];   // scores/probs [q][k']
  __shared__ float mL[64], lL[64], aL[64];
  const int t = threadIdx.x, lane = t & 63, wv = t >> 6;
  #pragma unroll
  for (int i = 0; i < 16; i++){
    int d = wv + (i << 2);
    Qt[d][lane] = Qp[(size_t)d*512 + q0 + lane];
  }
  if (t < 64){ mL[t] = -1e30f; lL[t] = 0.f; }
  float accA[16];
  #pragma unroll
  for (int j = 0; j < 16; j++) accA[j] = 0.f;
  const float sc = 0.044194173824159216f;   // 1/sqrt(512) (=F, per reference)

  for (int k0 = 0; k0 < 512; k0 += 32){
    __syncthreads();   // protect LDS reuse from previous iteration
    {
      int kk = t & 31, db = t >> 5;
      #pragma unroll
      for (int i = 0; i < 8; i++){
        int d = db + (i << 3);
        float kvK = Kp[(size_t)d*512 + k0 + kk];
        float kvV = Vp[(size_t)d*512 + k0 + kk];
        Kt[d][kk] = kvK;
        Vt[kk][d] = kvV;
      }
    }
    __syncthreads();
    // ---- S: thread (wv, lane): q rows qb..qb+7, col kk ----
    {
      int kk = lane & 31;
      int qb = (wv << 4) + ((lane >> 5) << 3);
      float s[8];
      #pragma unroll
      for (int j = 0; j < 8; j++) s[j] = 0.f;
      #pragma unroll 4
      for (int d = 0; d < 64; d++){
        float kv = Kt[d][kk];
        const float4 qa = *(const float4*)&Qt[d][qb];
        const float4 qc = *(const float4*)&Qt[d][qb + 4];
        s[0] += qa.x*kv; s[1] += qa.y*kv; s[2] += qa.z*kv; s[3] += qa.w*kv;
        s[4] += qc.x*kv; s[5] += qc.y*kv; s[6] += qc.z*kv; s[7] += qc.w*kv;
      }
      #pragma unroll
      for (int j = 0; j < 8; j++) St[qb + j][kk] = s[j] * sc;
    }
    __syncthreads();
    // ---- online softmax: 4 threads per row, 8 elems each ----
    {
      int r = t >> 2, sub = t & 3;
      float* row = &St[r][sub << 3];
      float4 x0 = ((float4*)row)[0], x1 = ((float4*)row)[1];
      float mx = fmaxf(fmaxf(fmaxf(x0.x,x0.y),fmaxf(x0.z,x0.w)),
                       fmaxf(fmaxf(x1.x,x1.y),fmaxf(x1.z,x1.w)));
      mx = fmaxf(mx, __shfl_xor(mx, 1));
      mx = fmaxf(mx, __shfl_xor(mx, 2));
      float mo = mL[r];
      float mn = fmaxf(mo, mx);
      float al = __expf(mo - mn);
      x0.x=__expf(x0.x-mn); x0.y=__expf(x0.y-mn); x0.z=__expf(x0.z-mn); x0.w=__expf(x0.w-mn);
      x1.x=__expf(x1.x-mn); x1.y=__expf(x1.y-mn); x1.z=__expf(x1.z-mn); x1.w=__expf(x1.w-mn);
      float sm = (x0.x+x0.y+x0.z+x0.w) + (x1.x+x1.y+x1.z+x1.w);
      sm += __shfl_xor(sm, 1);
      sm += __shfl_xor(sm, 2);
      ((float4*)row)[0]=x0; ((float4*)row)[1]=x1;
      if (sub == 0){ mL[r] = mn; lL[r] = lL[r]*al + sm; aL[r] = al; }
    }
    __syncthreads();
    // ---- A[d=lane][q=wv*16+j] += P * V ----
    #pragma unroll
    for (int j = 0; j < 16; j++) accA[j] *= aL[(wv << 4) + j];
    #pragma unroll
    for (int kj = 0; kj < 32; kj += 4){
      float v0 = Vt[kj][lane], v1 = Vt[kj+1][lane], v2 = Vt[kj+2][lane], v3 = Vt[kj+3][lane];
      #pragma unroll
      for (int j = 0; j < 16; j++){
        const float4 p = *(const float4*)&St[(wv << 4) + j][kj];
        accA[j] += p.x*v0 + p.y*v1 + p.z*v2 + p.w*v3;
      }
    }
  }
  __syncthreads();
  // normalize, stage transposed via Qt[d][q], write coalesced
  #pragma unroll
  for (int j = 0; j < 16; j++){
    float inv = 1.f / lL[(wv << 4) + j];
    Qt[lane][(wv << 4) + j] = accA[j] * inv;
  }
  __syncthreads();
  {
    int d = t >> 2, sub = t & 3;
    float* dst = &Op[(size_t)d*512 + q0 + (sub << 4)];
    const float* src = &Qt[d][sub << 4];
    float4 o0, o1, o2, o3;
    o0.x=src[0];  o0.y=src[1];  o0.z=src[2];  o0.w=src[3];
    o1.x=src[4];  o1.y=src[5];  o1.z=src[6];  o1.w=src[7];
    o2.x=src[8];  o2.y=src[9];  o2.z=src[10]; o2.w=src[11];
    o3.x=src[12]; o3.y=src[13]; o3.z=src[14]; o3.w=src[15];
    ((float4*)dst)[0]=o0; ((float4*)dst)[1]=o1; ((float4*)dst)[2]=o2; ((float4*)dst)[3]=o3;
  }
}

extern "C" void kernel_launch(void* const* d_in, const int* in_sizes, int n_in,
                              void* d_out, int out_size, void* d_ws, size_t ws_size,
                              hipStream_t stream) {
  (void)in_sizes; (void)n_in; (void)out_size; (void)ws_size;
  const float* x     = (const float*)d_in[0];
  const float* e1_pw = (const float*)d_in[1];
  const float* e1_dw = (const float*)d_in[2];
  const float* e2_pw = (const float*)d_in[3];
  const float* e2_dw = (const float*)d_in[4];
  const float* ei_pw = (const float*)d_in[5];
  const float* ei_dw = (const float*)d_in[6];
  const float* n1_w  = (const float*)d_in[7];
  const float* n1_b  = (const float*)d_in[8];
  const float* q_pw  = (const float*)d_in[9];
  const float* q_dw  = (const float*)d_in[10];
  const float* k_pw  = (const float*)d_in[11];
  const float* k_dw  = (const float*)d_in[12];
  const float* v_pw  = (const float*)d_in[13];
  const float* v_dw  = (const float*)d_in[14];
  const float* o_pw  = (const float*)d_in[15];
  const float* n2_w  = (const float*)d_in[16];
  const float* n2_b  = (const float*)d_in[17];
  const float* f1_pw = (const float*)d_in[18];
  const float* f2_pw = (const float*)d_in[19];
  const float* d1_pw = (const float*)d_in[20];
  const float* d1_dw = (const float*)d_in[21];
  const float* d2_pw = (const float*)d_in[22];
  const float* d2_dw = (const float*)d_in[23];
  const float* di_pw = (const float*)d_in[24];
  const float* di_dw = (const float*)d_in[25];

  // ---- workspace layout (floats). Total = 6,328,320 fl = 25.3 MB ----
  float* W    = (float*)d_ws;
  float* bufA = W;                      // [0, 1M)
  float* eB   = W + 1048576;            // [1M, 2M)
  float* pool = W + 2097152;            // [2M, 6M): qB/kB/vB + FFN mid + enc/dec tmp
  float* qB   = pool;                   // 1M
  float* kB   = pool + 1048576;         // 1M
  float* vB   = pool + 2097152;         // 1M
  float* MU   = W + 6291456;            // 2048
  float* RS   = MU + 2048;              // 2048
  float* cosT = RS + 2048;              // 16384
  float* sinT = cosT + 16384;           // 16384
  float* os   = (float*)d_out;          // decoder scratch (2,2,1024,512)

  const dim3 blk(256);
  const dim3 g512(8, 8, 4), g1024(8, 16, 4), g2048(8, 32, 4);
  const dim3 gstat(64, 4), gattn(8, 8, 4);

  rope_tab_k<<<64, blk, 0, stream>>>(cosT, sinT);

  // ---- encoder frame_block (x: K=1024 -> F=512) ----
  gemm_k<0,false,false><<<g512, blk, 0, stream>>>(e1_pw, x, bufA, 512, 1024, nullptr,nullptr,nullptr,nullptr);
  dwmix_k<1><<<512, blk, 0, stream>>>(bufA, e1_dw, nullptr, qB, 512);
  gemm_k<0,false,false><<<g512, blk, 0, stream>>>(e2_pw, qB, bufA, 512, 512, nullptr,nullptr,nullptr,nullptr);
  dwmix_k<0><<<512, blk, 0, stream>>>(bufA, e2_dw, nullptr, kB, 512);
  gemm_k<0,false,false><<<g512, blk, 0, stream>>>(ei_pw, x, bufA, 512, 1024, nullptr,nullptr,nullptr,nullptr);
  dwmix_k<2><<<512, blk, 0, stream>>>(bufA, ei_dw, kB, eB, 512);

  // ---- 12 layers ----
  for (int i = 0; i < 12; i++){
    const float* n1w = n1_w + i*1024; const float* n1b = n1_b + i*1024;
    const float* n2w = n2_w + i*1024; const float* n2b = n2_b + i*1024;
    size_t qo = (size_t)i*524288, fo = (size_t)i*2097152;

    stats_k<<<gstat, blk, 0, stream>>>(eB, MU, RS);
    gemm_k<0,false,true><<<g512, blk, 0, stream>>>(q_pw + qo, eB, bufA, 512, 512, MU, RS, n1w, n1b);
    dwmix_rope_k<<<256, blk, 0, stream>>>(bufA, q_dw + i*4, qB, cosT, sinT);
    gemm_k<0,false,true><<<g512, blk, 0, stream>>>(k_pw + qo, eB, bufA, 512, 512, MU, RS, n1w, n1b);
    dwmix_rope_k<<<256, blk, 0, stream>>>(bufA, k_dw + i*4, kB, cosT, sinT);
    gemm_k<0,false,true><<<g512, blk, 0, stream>>>(v_pw + qo, eB, bufA, 512, 512, MU, RS, n1w, n1b);
    dwmix_k<0><<<512, blk, 0, stream>>>(bufA, v_dw + i*4, nullptr, vB, 512);
    attn_k<<<gattn, blk, 0, stream>>>(qB, kB, vB, bufA);
    gemm_k<0,true,false><<<g512, blk, 0, stream>>>(o_pw + qo, bufA, eB, 512, 512, nullptr,nullptr,nullptr,nullptr);

    stats_k<<<gstat, blk, 0, stream>>>(eB, MU, RS);
    // FFN mid uses the whole 4M pool (q/k/v dead now): (bc, 2048, 512)
    gemm_k<1,false,true><<<g2048, blk, 0, stream>>>(f1_pw + fo, eB, pool, 2048, 512, MU, RS, n2w, n2b);
    gemm_k<0,true,false><<<g512, blk, 0, stream>>>(f2_pw + fo, pool, eB, 512, 2048, nullptr,nullptr,nullptr,nullptr);
  }

  // ---- decoder frame_block (e: F=512 -> F_IN=1024); z in pool (2M) ----
  gemm_k<0,false,false><<<g1024, blk, 0, stream>>>(d1_pw, eB, os, 1024, 512, nullptr,nullptr,nullptr,nullptr);
  dwmix_k<1><<<1024, blk, 0, stream>>>(os, d1_dw, nullptr, pool, 1024);
  gemm_k<0,false,false><<<g1024, blk, 0, stream>>>(d2_pw, pool, os, 1024, 1024, nullptr,nullptr,nullptr,nullptr);
  dwmix_k<0><<<1024, blk, 0, stream>>>(os, d2_dw, nullptr, pool, 1024);
  gemm_k<0,false,false><<<g1024, blk, 0, stream>>>(di_pw, eB, os, 1024, 512, nullptr,nullptr,nullptr,nullptr);
  dwmix_k<2><<<1024, blk, 0, stream>>>(os, di_dw, pool, os, 1024);
}

// Round 3
// 3263.315 us; speedup vs baseline: 1.9368x; 1.9368x over previous
//
#include <hip/hip_runtime.h>
#include <math.h>

// FrameTransformer v3: split-bf16 MFMA GEMMs, activations in [bc][w][f] (f contiguous).
// GEMM: Y[bc][w][m] = sum_k A[c][m][k] * Act[bc][w][k]  via mfma_f32_16x16x32_bf16,
// 3-term split (hi*hi + hi*lo + lo*hi), 64x64 tile, BK=64, reg-prefetch staging.

typedef short s16x8 __attribute__((ext_vector_type(8)));
typedef float f32x4 __attribute__((ext_vector_type(4)));
#define MFMA(a,b,c) __builtin_amdgcn_mfma_f32_16x16x32_bf16(a,b,c,0,0,0)

__device__ __forceinline__ float4 ld4(const float* p){ return *(const float4*)p; }
__device__ __forceinline__ void st4(float* p, float4 v){ *(float4*)p = v; }
__device__ __forceinline__ float4 f4fma2(float a, float4 x, float b, float4 y){
  float4 r; r.x=a*x.x+b*y.x; r.y=a*x.y+b*y.y; r.z=a*x.z+b*y.z; r.w=a*x.w+b*y.w; return r;
}
__device__ __forceinline__ float4 f4add(float4 a, float4 b){
  float4 r; r.x=a.x+b.x; r.y=a.y+b.y; r.z=a.z+b.z; r.w=a.w+b.w; return r;
}
__device__ __forceinline__ float4 f4sqrelu(float4 a){
  float4 r;
  r.x = a.x>0.f ? a.x*a.x : 0.f; r.y = a.y>0.f ? a.y*a.y : 0.f;
  r.z = a.z>0.f ? a.z*a.z : 0.f; r.w = a.w>0.f ? a.w*a.w : 0.f;
  return r;
}

// split 8 floats -> bf16 hi/lo planes (truncation; lo captures residual, rel err ~2^-16)
__device__ __forceinline__ void cvt8(float4 a, float4 b, s16x8* hi, s16x8* lo){
  union { s16x8 v; unsigned short u[8]; } H, L;
  float f[8] = {a.x,a.y,a.z,a.w,b.x,b.y,b.z,b.w};
  #pragma unroll
  for (int j=0;j<8;j++){
    unsigned u = __float_as_uint(f[j]);
    H.u[j] = (unsigned short)(u>>16);
    float hf = __uint_as_float(u & 0xffff0000u);
    float lf = f[j] - hf;
    L.u[j] = (unsigned short)(__float_as_uint(lf)>>16);
  }
  *hi = H.v; *lo = L.v;
}

// ---------------- rope table: cos/sin[w][j], j=0..31 ----------------
__global__ __launch_bounds__(256) void rope_tab_k(float* __restrict__ cosT, float* __restrict__ sinT){
  int idx = blockIdx.x*256 + threadIdx.x;   // 512*32
  int w = idx >> 5, j = idx & 31;
  float th = (float)w * powf(10000.f, -(float)(2*j)/64.f);
  cosT[idx] = cosf(th);
  sinT[idx] = sinf(th);
}

// ---------------- frame-norm stats: one wave per (bc,w) row ----------------
__global__ __launch_bounds__(256) void stats_k(const float* __restrict__ E,
                                               float* __restrict__ MU, float* __restrict__ RS){
  int row = (blockIdx.x<<2) + (threadIdx.x>>6);
  int lane = threadIdx.x & 63;
  const float* p = E + (size_t)row*512 + (lane<<3);
  float4 a = ld4(p), b = ld4(p+4);
  float s = a.x+a.y+a.z+a.w + b.x+b.y+b.z+b.w;
  float q = a.x*a.x+a.y*a.y+a.z*a.z+a.w*a.w + b.x*b.x+b.y*b.y+b.z*b.z+b.w*b.w;
  #pragma unroll
  for (int off=32; off; off>>=1){ s += __shfl_xor(s,off); q += __shfl_xor(q,off); }
  if (lane==0){
    float mu = s*(1.f/512.f);
    float var = q*(1.f/512.f) - mu*mu;
    MU[row] = mu; RS[row] = rsqrtf(var + 1e-5f);
  }
}

// ---------------- MFMA GEMM ----------------
// Y[bc][w=n][m], tile 64(m)x64(n), 4 waves in 2x2 quadrants, BK=64.
// EPI: 0 none, 1 sq_relu. ACC: += into Y. NORM: frame-norm B rows while staging.
// FUSE3: z = proj*4+bc, A selected from A0/A1/A2, Y offset proj*1048576.
template<int EPI, bool ACC, bool NORM, bool FUSE3>
__global__ __launch_bounds__(256) void mm_k(
    const float* __restrict__ A0, const float* __restrict__ A1, const float* __restrict__ A2,
    const float* __restrict__ B_, float* __restrict__ Y_, int M, int K,
    const float* __restrict__ MU, const float* __restrict__ RS,
    const float* __restrict__ G, const float* __restrict__ Bt)
{
  const int z = blockIdx.z;
  const int bc = FUSE3 ? (z & 3) : z;
  const int c = bc & 1;
  const float* A = FUSE3 ? ((z>>2)==0 ? A0 : ((z>>2)==1 ? A1 : A2)) : A0;
  A += (size_t)c * M * K;
  const float* B = B_ + (size_t)bc * 512 * K;
  float* Y = Y_ + (FUSE3 ? (size_t)(z>>2)*1048576 : (size_t)0) + (size_t)bc * 512 * M;
  const int n0 = blockIdx.x << 6, m0 = blockIdx.y << 6;
  const int t = threadIdx.x;

  __shared__ __align__(16) unsigned char smem[36864];
  unsigned short* AsH = (unsigned short*)smem;        // [64][72]
  unsigned short* AsL = AsH + 4608;
  unsigned short* BsH = AsL + 4608;
  unsigned short* BsL = BsH + 4608;

  // staging coords: row sr (0..63), col chunk scB (0,16,32,48)
  const int sr = t >> 2, scB = (t & 3) << 4;
  const float* Ag = A + (size_t)(m0 + sr)*K + scB;
  const float* Bg = B + (size_t)(n0 + sr)*K + scB;
  float mu = 0.f, rs = 0.f;
  if (NORM){ mu = MU[bc*512 + n0 + sr]; rs = RS[bc*512 + n0 + sr]; }

  // compute coords
  const int wv = t >> 6, lane = t & 63;
  const int fr = lane & 15, fq = lane >> 4;
  const int mq = (wv >> 1) << 5, nq = (wv & 1) << 5;
  const int aB0 = (mq + fr)*72, aB1 = (mq + 16 + fr)*72;
  const int bB0 = (nq + fr)*72, bB1 = (nq + 16 + fr)*72;

  f32x4 acc00 = {0,0,0,0}, acc01 = {0,0,0,0}, acc10 = {0,0,0,0}, acc11 = {0,0,0,0};

  const int NT = K >> 6;
  float4 ra[4], rb[4];
  #pragma unroll
  for (int i=0;i<4;i++){ ra[i] = ld4(Ag + i*4); rb[i] = ld4(Bg + i*4); }

  for (int kt = 0; kt < NT; kt++){
    // convert + write to LDS
    float4 wb[4];
    #pragma unroll
    for (int i=0;i<4;i++){
      if (NORM){
        float4 g = ld4(&G[c*512 + kt*64 + scB + i*4]);
        float4 bb = ld4(&Bt[c*512 + kt*64 + scB + i*4]);
        float4 v = rb[i];
        v.x = (v.x-mu)*rs*g.x + bb.x; v.y = (v.y-mu)*rs*g.y + bb.y;
        v.z = (v.z-mu)*rs*g.z + bb.z; v.w = (v.w-mu)*rs*g.w + bb.w;
        wb[i] = v;
      } else wb[i] = rb[i];
    }
    {
      s16x8 h, l;
      cvt8(ra[0], ra[1], &h, &l);
      *(s16x8*)&AsH[sr*72 + scB]     = h; *(s16x8*)&AsL[sr*72 + scB]     = l;
      cvt8(ra[2], ra[3], &h, &l);
      *(s16x8*)&AsH[sr*72 + scB + 8] = h; *(s16x8*)&AsL[sr*72 + scB + 8] = l;
      cvt8(wb[0], wb[1], &h, &l);
      *(s16x8*)&BsH[sr*72 + scB]     = h; *(s16x8*)&BsL[sr*72 + scB]     = l;
      cvt8(wb[2], wb[3], &h, &l);
      *(s16x8*)&BsH[sr*72 + scB + 8] = h; *(s16x8*)&BsL[sr*72 + scB + 8] = l;
    }
    __syncthreads();
    // prefetch next tile while MFMAs run
    if (kt + 1 < NT){
      #pragma unroll
      for (int i=0;i<4;i++){
        ra[i] = ld4(Ag + (kt+1)*64 + i*4);
        rb[i] = ld4(Bg + (kt+1)*64 + i*4);
      }
    }
    #pragma unroll
    for (int ks = 0; ks < 64; ks += 32){
      const int ko = ks + fq*8;
      s16x8 aH0 = *(const s16x8*)&AsH[aB0 + ko];
      s16x8 aH1 = *(const s16x8*)&AsH[aB1 + ko];
      s16x8 aL0 = *(const s16x8*)&AsL[aB0 + ko];
      s16x8 aL1 = *(const s16x8*)&AsL[aB1 + ko];
      s16x8 bH0 = *(const s16x8*)&BsH[bB0 + ko];
      s16x8 bH1 = *(const s16x8*)&BsH[bB1 + ko];
      s16x8 bL0 = *(const s16x8*)&BsL[bB0 + ko];
      s16x8 bL1 = *(const s16x8*)&BsL[bB1 + ko];
      acc00 = MFMA(aH0,bH0,acc00); acc00 = MFMA(aH0,bL0,acc00); acc00 = MFMA(aL0,bH0,acc00);
      acc01 = MFMA(aH0,bH1,acc01); acc01 = MFMA(aH0,bL1,acc01); acc01 = MFMA(aL0,bH1,acc01);
      acc10 = MFMA(aH1,bH0,acc10); acc10 = MFMA(aH1,bL0,acc10); acc10 = MFMA(aL1,bH0,acc10);
      acc11 = MFMA(aH1,bH1,acc11); acc11 = MFMA(aH1,bL1,acc11); acc11 = MFMA(aL1,bH1,acc11);
    }
    __syncthreads();
  }

  // epilogue: stage Yt[n][m] (stride 72), then coalesced rows of Y[w][m]
  float* Yt = (float*)smem;    // [64][72]
  #pragma unroll
  for (int i=0;i<4;i++){
    Yt[(nq      + fr)*72 + mq      + fq*4 + i] = acc00[i];
    Yt[(nq + 16 + fr)*72 + mq      + fq*4 + i] = acc01[i];
    Yt[(nq      + fr)*72 + mq + 16 + fq*4 + i] = acc10[i];
    Yt[(nq + 16 + fr)*72 + mq + 16 + fq*4 + i] = acc11[i];
  }
  __syncthreads();
  #pragma unroll
  for (int i=0;i<4;i++){
    float4 r = *(float4*)&Yt[sr*72 + scB + i*4];
    if (EPI == 1) r = f4sqrelu(r);
    float* dst = &Y[(size_t)(n0 + sr)*M + m0 + scB + i*4];
    if (ACC) r = f4add(r, ld4(dst));
    st4(dst, r);
  }
}

// ---------------- channel mix (dw), flat elementwise over [c][F*512] ----------------
// MODE: 0 none, 1 sq_relu, 2 add Z
template<int MODE>
__global__ __launch_bounds__(256) void dwmix_k(
    const float* __restrict__ T, const float* __restrict__ dwp,
    const float* __restrict__ Z, float* __restrict__ O, int F)
{
  int idx = blockIdx.x*256 + threadIdx.x;
  int perb = F << 7;                 // F*512/4 float4-groups per channel
  int b = idx / perb; int rem = idx - b*perb;
  size_t i0 = ((size_t)(b*2) * F)*512 + (size_t)rem*4;
  size_t i1 = i0 + (size_t)F*512;
  float4 t0 = ld4(T + i0), t1 = ld4(T + i1);
  float d00 = dwp[0], d01 = dwp[1], d10 = dwp[2], d11 = dwp[3];
  float4 o0 = f4fma2(d00, t0, d01, t1);
  float4 o1 = f4fma2(d10, t0, d11, t1);
  if (MODE == 1){ o0 = f4sqrelu(o0); o1 = f4sqrelu(o1); }
  if (MODE == 2){ o0 = f4add(o0, ld4(Z + i0)); o1 = f4add(o1, ld4(Z + i1)); }
  st4(O + i0, o0);
  st4(O + i1, o1);
}

// ---------------- fused qkv post: dw-mix (+rope for q,k), wf layout ----------------
__global__ __launch_bounds__(256) void qkv_post_k(
    const float* __restrict__ QY, const float* __restrict__ qdw,
    const float* __restrict__ kdw, const float* __restrict__ vdw,
    float* __restrict__ qB, float* __restrict__ kB, float* __restrict__ vB,
    const float* __restrict__ cosT, const float* __restrict__ sinT)
{
  int p = blockIdx.y;
  const float* T = QY + (size_t)p*1048576;
  const float* dwp = (p==0) ? qdw : ((p==1) ? kdw : vdw);
  float* O = (p==0) ? qB : ((p==1) ? kB : vB);
  int idx = blockIdx.x*256 + threadIdx.x;    // 2 * 512 * 128
  int b = idx >> 16; int rem = idx & 65535;
  int w = rem >> 7; int f = (rem & 127) << 2;
  size_t i0 = ((size_t)(b*2)*512 + w)*512 + f;
  size_t i1 = i0 + 262144;
  float4 t0 = ld4(T+i0), t1 = ld4(T+i1);
  float d00 = dwp[0], d01 = dwp[1], d10 = dwp[2], d11 = dwp[3];
  float4 o0 = f4fma2(d00, t0, d01, t1);
  float4 o1 = f4fma2(d10, t0, d11, t1);
  if (p < 2){
    int j = (f & 63) >> 1;
    float c0 = cosT[w*32 + j], c1 = cosT[w*32 + j + 1];
    float s0 = sinT[w*32 + j], s1 = sinT[w*32 + j + 1];
    float4 r0, r1;
    r0.x = o0.x*c0 - o0.y*s0;  r0.y = o0.y*c0 + o0.x*s0;
    r0.z = o0.z*c1 - o0.w*s1;  r0.w = o0.w*c1 + o0.z*s1;
    r1.x = o1.x*c0 - o1.y*s0;  r1.y = o1.y*c0 + o1.x*s0;
    r1.z = o1.z*c1 - o1.w*s1;  r1.w = o1.w*c1 + o1.z*s1;
    o0 = r0; o1 = r1;
  }
  st4(O + i0, o0);
  st4(O + i1, o1);
}

// ---------------- transpose x: [bc][1024 f][512 w] -> [bc][512 w][1024 f] ----------------
__global__ __launch_bounds__(256) void transpose_x_k(const float* __restrict__ X, float* __restrict__ XT){
  __shared__ float T[64][68];
  int w0 = blockIdx.x << 6, f0 = blockIdx.y << 6, bc = blockIdx.z;
  int r = threadIdx.x >> 2, c4 = (threadIdx.x & 3) << 4;
  const float* src = X + ((size_t)bc*1024 + f0 + r)*512 + w0 + c4;
  #pragma unroll
  for (int i=0;i<4;i++) st4(&T[r][c4 + i*4], ld4(src + i*4));
  __syncthreads();
  float* dst = XT + ((size_t)bc*512 + w0 + r)*1024 + f0 + c4;
  #pragma unroll
  for (int i=0;i<4;i++){
    float4 v;
    v.x = T[c4+i*4+0][r]; v.y = T[c4+i*4+1][r]; v.z = T[c4+i*4+2][r]; v.w = T[c4+i*4+3][r];
    st4(dst + i*4, v);
  }
}

// ---------------- final: dw-mix + add Z, transpose wf -> (b,c,1024,512) ----------------
__global__ __launch_bounds__(256) void out_t_k(const float* __restrict__ T_, const float* __restrict__ dwp,
                                               const float* __restrict__ Z, float* __restrict__ O){
  __shared__ float T0[64][68], T1[64][68];
  int w0 = blockIdx.x << 6, f0 = blockIdx.y << 6, b = blockIdx.z;
  int r = threadIdx.x >> 2, c4 = (threadIdx.x & 3) << 4;
  size_t base0 = ((size_t)(b*2)*512 + w0 + r)*1024 + f0 + c4;
  size_t base1 = base0 + 524288;
  float d00 = dwp[0], d01 = dwp[1], d10 = dwp[2], d11 = dwp[3];
  #pragma unroll
  for (int i=0;i<4;i++){
    float4 t0 = ld4(T_+base0+i*4), t1 = ld4(T_+base1+i*4);
    float4 z0 = ld4(Z+base0+i*4),  z1 = ld4(Z+base1+i*4);
    st4(&T0[r][c4+i*4], f4add(f4fma2(d00,t0,d01,t1), z0));
    st4(&T1[r][c4+i*4], f4add(f4fma2(d10,t0,d11,t1), z1));
  }
  __syncthreads();
  size_t ob0 = ((size_t)(b*2)*1024 + f0 + r)*512 + w0 + c4;
  size_t ob1 = ob0 + 524288;
  #pragma unroll
  for (int i=0;i<4;i++){
    float4 v0, v1;
    v0.x=T0[c4+i*4+0][r]; v0.y=T0[c4+i*4+1][r]; v0.z=T0[c4+i*4+2][r]; v0.w=T0[c4+i*4+3][r];
    v1.x=T1[c4+i*4+0][r]; v1.y=T1[c4+i*4+1][r]; v1.z=T1[c4+i*4+2][r]; v1.w=T1[c4+i*4+3][r];
    st4(O+ob0+i*4, v0);
    st4(O+ob1+i*4, v1);
  }
}

// ---------------- fused attention, wf layout ----------------
// grid (8 q-tiles, 8 heads, 4 bc); block 256 = 4 waves. K-tile = 32.
__global__ __launch_bounds__(256) void attn_k(
    const float* __restrict__ Q, const float* __restrict__ K,
    const float* __restrict__ V, float* __restrict__ O)
{
  const int q0 = blockIdx.x << 6;
  const int h  = blockIdx.y;
  const int bc = blockIdx.z;
  const size_t cb = (size_t)bc*262144;
  const int hc = h*64;
  const float* Qp = Q + cb;
  const float* Kp = K + cb;
  const float* Vp = V + cb;
  float*       Op = O + cb;
  __shared__ float Qt[64][68];   // [d][q]
  __shared__ float Kt[64][33];   // [d][k']
  __shared__ float Vt[32][68];   // [k'][d]
  __shared__ float St[64][36];   // [q][k']
  __shared__ float mL[64], lL[64], aL[64];
  const int t = threadIdx.x, lane = t & 63, wv = t >> 6;
  {
    int r = t >> 2, c4 = (t & 3) << 4;
    #pragma unroll
    for (int i=0;i<4;i++){
      float4 v = ld4(&Qp[(size_t)(q0+r)*512 + hc + c4 + i*4]);
      Qt[c4+i*4+0][r]=v.x; Qt[c4+i*4+1][r]=v.y; Qt[c4+i*4+2][r]=v.z; Qt[c4+i*4+3][r]=v.w;
    }
  }
  if (t < 64){ mL[t] = -1e30f; lL[t] = 0.f; }
  float accA[16];
  #pragma unroll
  for (int j = 0; j < 16; j++) accA[j] = 0.f;
  const float sc = 0.044194173824159216f;   // 1/sqrt(512) (=F, per reference)

  for (int k0 = 0; k0 < 512; k0 += 32){
    __syncthreads();
    {
      int kr = t >> 3, c8 = (t & 7) << 3;
      #pragma unroll
      for (int i=0;i<2;i++){
        float4 v = ld4(&Kp[(size_t)(k0+kr)*512 + hc + c8 + i*4]);
        Kt[c8+i*4+0][kr]=v.x; Kt[c8+i*4+1][kr]=v.y; Kt[c8+i*4+2][kr]=v.z; Kt[c8+i*4+3][kr]=v.w;
        float4 u = ld4(&Vp[(size_t)(k0+kr)*512 + hc + c8 + i*4]);
        st4(&Vt[kr][c8 + i*4], u);
      }
    }
    __syncthreads();
    // S = Q^T K: thread covers 8 q-rows x 1 col kk
    {
      int kk = lane & 31;
      int qb = (wv << 4) + ((lane >> 5) << 3);
      float s[8];
      #pragma unroll
      for (int j = 0; j < 8; j++) s[j] = 0.f;
      #pragma unroll 4
      for (int d = 0; d < 64; d++){
        float kv = Kt[d][kk];
        const float4 qa = *(const float4*)&Qt[d][qb];
        const float4 qc = *(const float4*)&Qt[d][qb + 4];
        s[0] += qa.x*kv; s[1] += qa.y*kv; s[2] += qa.z*kv; s[3] += qa.w*kv;
        s[4] += qc.x*kv; s[5] += qc.y*kv; s[6] += qc.z*kv; s[7] += qc.w*kv;
      }
      #pragma unroll
      for (int j = 0; j < 8; j++) St[qb + j][kk] = s[j] * sc;
    }
    __syncthreads();
    // online softmax: 4 threads per row
    {
      int r = t >> 2, sub = t & 3;
      float* row = &St[r][sub << 3];
      float4 x0 = ((float4*)row)[0], x1 = ((float4*)row)[1];
      float mx = fmaxf(fmaxf(fmaxf(x0.x,x0.y),fmaxf(x0.z,x0.w)),
                       fmaxf(fmaxf(x1.x,x1.y),fmaxf(x1.z,x1.w)));
      mx = fmaxf(mx, __shfl_xor(mx, 1));
      mx = fmaxf(mx, __shfl_xor(mx, 2));
      float mo = mL[r];
      float mn = fmaxf(mo, mx);
      float al = __expf(mo - mn);
      x0.x=__expf(x0.x-mn); x0.y=__expf(x0.y-mn); x0.z=__expf(x0.z-mn); x0.w=__expf(x0.w-mn);
      x1.x=__expf(x1.x-mn); x1.y=__expf(x1.y-mn); x1.z=__expf(x1.z-mn); x1.w=__expf(x1.w-mn);
      float sm = (x0.x+x0.y+x0.z+x0.w) + (x1.x+x1.y+x1.z+x1.w);
      sm += __shfl_xor(sm, 1);
      sm += __shfl_xor(sm, 2);
      ((float4*)row)[0]=x0; ((float4*)row)[1]=x1;
      if (sub == 0){ mL[r] = mn; lL[r] = lL[r]*al + sm; aL[r] = al; }
    }
    __syncthreads();
    // A[d=lane][q=wv*16+j] += P * V
    #pragma unroll
    for (int j = 0; j < 16; j++) accA[j] *= aL[(wv << 4) + j];
    #pragma unroll
    for (int kj = 0; kj < 32; kj += 4){
      float v0 = Vt[kj][lane], v1 = Vt[kj+1][lane], v2 = Vt[kj+2][lane], v3 = Vt[kj+3][lane];
      #pragma unroll
      for (int j = 0; j < 16; j++){
        const float4 p = *(const float4*)&St[(wv << 4) + j][kj];
        accA[j] += p.x*v0 + p.y*v1 + p.z*v2 + p.w*v3;
      }
    }
  }
  // write out: row w = q, col f = hc + lane (coalesced)
  #pragma unroll
  for (int j = 0; j < 16; j++){
    int q = (wv << 4) + j;
    Op[(size_t)(q0 + q)*512 + hc + lane] = accA[j] / lL[q];
  }
}

extern "C" void kernel_launch(void* const* d_in, const int* in_sizes, int n_in,
                              void* d_out, int out_size, void* d_ws, size_t ws_size,
                              hipStream_t stream) {
  (void)in_sizes; (void)n_in; (void)out_size; (void)ws_size;
  const float* x     = (const float*)d_in[0];
  const float* e1_pw = (const float*)d_in[1];
  const float* e1_dw = (const float*)d_in[2];
  const float* e2_pw = (const float*)d_in[3];
  const float* e2_dw = (const float*)d_in[4];
  const float* ei_pw = (const float*)d_in[5];
  const float* ei_dw = (const float*)d_in[6];
  const float* n1_w  = (const float*)d_in[7];
  const float* n1_b  = (const float*)d_in[8];
  const float* q_pw  = (const float*)d_in[9];
  const float* q_dw  = (const float*)d_in[10];
  const float* k_pw  = (const float*)d_in[11];
  const float* k_dw  = (const float*)d_in[12];
  const float* v_pw  = (const float*)d_in[13];
  const float* v_dw  = (const float*)d_in[14];
  const float* o_pw  = (const float*)d_in[15];
  const float* n2_w  = (const float*)d_in[16];
  const float* n2_b  = (const float*)d_in[17];
  const float* f1_pw = (const float*)d_in[18];
  const float* f2_pw = (const float*)d_in[19];
  const float* d1_pw = (const float*)d_in[20];
  const float* d1_dw = (const float*)d_in[21];
  const float* d2_pw = (const float*)d_in[22];
  const float* d2_dw = (const float*)d_in[23];
  const float* di_pw = (const float*)d_in[24];
  const float* di_dw = (const float*)d_in[25];

  // ws layout (floats): bufA 3M | eB 1M | R 4M | MU/RS/cos/sin  => 8.04M fl = 32.2 MB
  float* W    = (float*)d_ws;
  float* bufA = W;                       // 3M (qkv out / attn out / dec gemm out)
  float* eB   = W + 3145728;             // 1M
  float* R    = W + 4194304;             // 4M pool
  float* qB   = R;                       // 1M (layer phase)
  float* kB   = R + 1048576;
  float* vB   = R + 2097152;
  float* pool = R;                       // 4M (FFN mid; qkv dead by then)
  float* xT   = R;                       // 2M (encoder phase)
  float* MU   = W + 8388608;             // 2048
  float* RS   = MU + 2048;               // 2048
  float* cosT = RS + 2048;               // 16384
  float* sinT = cosT + 16384;            // 16384
  float* os   = (float*)d_out;

  const float* NP = nullptr;
  const dim3 blk(256);

  rope_tab_k<<<64, blk, 0, stream>>>(cosT, sinT);
  transpose_x_k<<<dim3(8,16,4), blk, 0, stream>>>(x, xT);

  // ---- encoder frame_block (xT: K=1024 -> F=512), wf layout ----
  mm_k<0,false,false,false><<<dim3(8,8,4), blk, 0, stream>>>(e1_pw,NP,NP, xT, bufA, 512, 1024, NP,NP,NP,NP);
  dwmix_k<1><<<512, blk, 0, stream>>>(bufA, e1_dw, NP, R + 2097152, 512);            // t -> R+2M (1M)
  mm_k<0,false,false,false><<<dim3(8,8,4), blk, 0, stream>>>(e2_pw,NP,NP, R + 2097152, bufA, 512, 512, NP,NP,NP,NP);
  dwmix_k<0><<<512, blk, 0, stream>>>(bufA, e2_dw, NP, R + 3145728, 512);            // t2 -> R+3M (1M)
  mm_k<0,false,false,false><<<dim3(8,8,4), blk, 0, stream>>>(ei_pw,NP,NP, xT, bufA, 512, 1024, NP,NP,NP,NP);
  dwmix_k<2><<<512, blk, 0, stream>>>(bufA, ei_dw, R + 3145728, eB, 512);

  // ---- 12 layers ----
  for (int i = 0; i < 12; i++){
    const float* n1w = n1_w + i*1024; const float* n1b = n1_b + i*1024;
    const float* n2w = n2_w + i*1024; const float* n2b = n2_b + i*1024;
    size_t qo = (size_t)i*524288, fo = (size_t)i*2097152;

    stats_k<<<512, blk, 0, stream>>>(eB, MU, RS);
    mm_k<0,false,true,true><<<dim3(8,8,12), blk, 0, stream>>>(q_pw+qo, k_pw+qo, v_pw+qo, eB, bufA, 512, 512, MU, RS, n1w, n1b);
    qkv_post_k<<<dim3(512,3), blk, 0, stream>>>(bufA, q_dw+i*4, k_dw+i*4, v_dw+i*4, qB, kB, vB, cosT, sinT);
    attn_k<<<dim3(8,8,4), blk, 0, stream>>>(qB, kB, vB, bufA);
    mm_k<0,true,false,false><<<dim3(8,8,4), blk, 0, stream>>>(o_pw+qo,NP,NP, bufA, eB, 512, 512, NP,NP,NP,NP);

    stats_k<<<512, blk, 0, stream>>>(eB, MU, RS);
    mm_k<1,false,true,false><<<dim3(8,32,4), blk, 0, stream>>>(f1_pw+fo,NP,NP, eB, pool, 2048, 512, MU, RS, n2w, n2b);
    mm_k<0,true,false,false><<<dim3(8,8,4), blk, 0, stream>>>(f2_pw+fo,NP,NP, pool, eB, 512, 2048, NP,NP,NP,NP);
  }

  // ---- decoder frame_block (eB: F=512 -> F_IN=1024), wf layout ----
  mm_k<0,false,false,false><<<dim3(8,16,4), blk, 0, stream>>>(d1_pw,NP,NP, eB, bufA, 1024, 512, NP,NP,NP,NP);
  dwmix_k<1><<<1024, blk, 0, stream>>>(bufA, d1_dw, NP, R + 2097152, 1024);          // t1 -> R+2M (2M)
  mm_k<0,false,false,false><<<dim3(8,16,4), blk, 0, stream>>>(d2_pw,NP,NP, R + 2097152, bufA, 1024, 1024, NP,NP,NP,NP);
  dwmix_k<0><<<1024, blk, 0, stream>>>(bufA, d2_dw, NP, R, 1024);                    // t2 -> R (2M)
  mm_k<0,false,false,false><<<dim3(8,16,4), blk, 0, stream>>>(di_pw,NP,NP, eB, bufA, 1024, 512, NP,NP,NP,NP);
  out_t_k<<<dim3(8,16,2), blk, 0, stream>>>(bufA, di_dw, R, os);
}

// Round 4
// 2395.940 us; speedup vs baseline: 2.6379x; 1.3620x over previous
//
#include <hip/hip_runtime.h>
#include <math.h>

// FrameTransformer v4: split-bf16 MFMA GEMMs AND MFMA attention.
// Activations in [bc][w][f] (f contiguous).
// GEMM: Y[bc][w][m] = sum_k A[c][m][k] * Act[bc][w][k]  via mfma_f32_16x16x32_bf16,
// 3-term split (hi*hi + hi*lo + lo*hi), 64x64 tile, BK=64, reg-prefetch staging.

typedef short s16x8 __attribute__((ext_vector_type(8)));
typedef float f32x4 __attribute__((ext_vector_type(4)));
#define MFMA(a,b,c) __builtin_amdgcn_mfma_f32_16x16x32_bf16(a,b,c,0,0,0)

__device__ __forceinline__ float4 ld4(const float* p){ return *(const float4*)p; }
__device__ __forceinline__ void st4(float* p, float4 v){ *(float4*)p = v; }
__device__ __forceinline__ float4 f4fma2(float a, float4 x, float b, float4 y){
  float4 r; r.x=a*x.x+b*y.x; r.y=a*x.y+b*y.y; r.z=a*x.z+b*y.z; r.w=a*x.w+b*y.w; return r;
}
__device__ __forceinline__ float4 f4add(float4 a, float4 b){
  float4 r; r.x=a.x+b.x; r.y=a.y+b.y; r.z=a.z+b.z; r.w=a.w+b.w; return r;
}
__device__ __forceinline__ float4 f4sqrelu(float4 a){
  float4 r;
  r.x = a.x>0.f ? a.x*a.x : 0.f; r.y = a.y>0.f ? a.y*a.y : 0.f;
  r.z = a.z>0.f ? a.z*a.z : 0.f; r.w = a.w>0.f ? a.w*a.w : 0.f;
  return r;
}

// split 8 floats -> bf16 hi/lo planes (truncation; lo captures residual, rel err ~2^-16)
__device__ __forceinline__ void cvt8(float4 a, float4 b, s16x8* hi, s16x8* lo){
  union { s16x8 v; unsigned short u[8]; } H, L;
  float f[8] = {a.x,a.y,a.z,a.w,b.x,b.y,b.z,b.w};
  #pragma unroll
  for (int j=0;j<8;j++){
    unsigned u = __float_as_uint(f[j]);
    H.u[j] = (unsigned short)(u>>16);
    float hf = __uint_as_float(u & 0xffff0000u);
    float lf = f[j] - hf;
    L.u[j] = (unsigned short)(__float_as_uint(lf)>>16);
  }
  *hi = H.v; *lo = L.v;
}

// ---------------- rope table: cos/sin[w][j], j=0..31 ----------------
__global__ __launch_bounds__(256) void rope_tab_k(float* __restrict__ cosT, float* __restrict__ sinT){
  int idx = blockIdx.x*256 + threadIdx.x;   // 512*32
  int w = idx >> 5, j = idx & 31;
  float th = (float)w * powf(10000.f, -(float)(2*j)/64.f);
  cosT[idx] = cosf(th);
  sinT[idx] = sinf(th);
}

// ---------------- frame-norm stats: one wave per (bc,w) row ----------------
__global__ __launch_bounds__(256) void stats_k(const float* __restrict__ E,
                                               float* __restrict__ MU, float* __restrict__ RS){
  int row = (blockIdx.x<<2) + (threadIdx.x>>6);
  int lane = threadIdx.x & 63;
  const float* p = E + (size_t)row*512 + (lane<<3);
  float4 a = ld4(p), b = ld4(p+4);
  float s = a.x+a.y+a.z+a.w + b.x+b.y+b.z+b.w;
  float q = a.x*a.x+a.y*a.y+a.z*a.z+a.w*a.w + b.x*b.x+b.y*b.y+b.z*b.z+b.w*b.w;
  #pragma unroll
  for (int off=32; off; off>>=1){ s += __shfl_xor(s,off); q += __shfl_xor(q,off); }
  if (lane==0){
    float mu = s*(1.f/512.f);
    float var = q*(1.f/512.f) - mu*mu;
    MU[row] = mu; RS[row] = rsqrtf(var + 1e-5f);
  }
}

// ---------------- MFMA GEMM ----------------
template<int EPI, bool ACC, bool NORM, bool FUSE3>
__global__ __launch_bounds__(256) void mm_k(
    const float* __restrict__ A0, const float* __restrict__ A1, const float* __restrict__ A2,
    const float* __restrict__ B_, float* __restrict__ Y_, int M, int K,
    const float* __restrict__ MU, const float* __restrict__ RS,
    const float* __restrict__ G, const float* __restrict__ Bt)
{
  const int z = blockIdx.z;
  const int bc = FUSE3 ? (z & 3) : z;
  const int c = bc & 1;
  const float* A = FUSE3 ? ((z>>2)==0 ? A0 : ((z>>2)==1 ? A1 : A2)) : A0;
  A += (size_t)c * M * K;
  const float* B = B_ + (size_t)bc * 512 * K;
  float* Y = Y_ + (FUSE3 ? (size_t)(z>>2)*1048576 : (size_t)0) + (size_t)bc * 512 * M;
  const int n0 = blockIdx.x << 6, m0 = blockIdx.y << 6;
  const int t = threadIdx.x;

  __shared__ __align__(16) unsigned char smem[36864];
  unsigned short* AsH = (unsigned short*)smem;        // [64][72]
  unsigned short* AsL = AsH + 4608;
  unsigned short* BsH = AsL + 4608;
  unsigned short* BsL = BsH + 4608;

  const int sr = t >> 2, scB = (t & 3) << 4;
  const float* Ag = A + (size_t)(m0 + sr)*K + scB;
  const float* Bg = B + (size_t)(n0 + sr)*K + scB;
  float mu = 0.f, rs = 0.f;
  if (NORM){ mu = MU[bc*512 + n0 + sr]; rs = RS[bc*512 + n0 + sr]; }

  const int wv = t >> 6, lane = t & 63;
  const int fr = lane & 15, fq = lane >> 4;
  const int mq = (wv >> 1) << 5, nq = (wv & 1) << 5;
  const int aB0 = (mq + fr)*72, aB1 = (mq + 16 + fr)*72;
  const int bB0 = (nq + fr)*72, bB1 = (nq + 16 + fr)*72;

  f32x4 acc00 = {0,0,0,0}, acc01 = {0,0,0,0}, acc10 = {0,0,0,0}, acc11 = {0,0,0,0};

  const int NT = K >> 6;
  float4 ra[4], rb[4];
  #pragma unroll
  for (int i=0;i<4;i++){ ra[i] = ld4(Ag + i*4); rb[i] = ld4(Bg + i*4); }

  for (int kt = 0; kt < NT; kt++){
    float4 wb[4];
    #pragma unroll
    for (int i=0;i<4;i++){
      if (NORM){
        float4 g = ld4(&G[c*512 + kt*64 + scB + i*4]);
        float4 bb = ld4(&Bt[c*512 + kt*64 + scB + i*4]);
        float4 v = rb[i];
        v.x = (v.x-mu)*rs*g.x + bb.x; v.y = (v.y-mu)*rs*g.y + bb.y;
        v.z = (v.z-mu)*rs*g.z + bb.z; v.w = (v.w-mu)*rs*g.w + bb.w;
        wb[i] = v;
      } else wb[i] = rb[i];
    }
    {
      s16x8 h, l;
      cvt8(ra[0], ra[1], &h, &l);
      *(s16x8*)&AsH[sr*72 + scB]     = h; *(s16x8*)&AsL[sr*72 + scB]     = l;
      cvt8(ra[2], ra[3], &h, &l);
      *(s16x8*)&AsH[sr*72 + scB + 8] = h; *(s16x8*)&AsL[sr*72 + scB + 8] = l;
      cvt8(wb[0], wb[1], &h, &l);
      *(s16x8*)&BsH[sr*72 + scB]     = h; *(s16x8*)&BsL[sr*72 + scB]     = l;
      cvt8(wb[2], wb[3], &h, &l);
      *(s16x8*)&BsH[sr*72 + scB + 8] = h; *(s16x8*)&BsL[sr*72 + scB + 8] = l;
    }
    __syncthreads();
    if (kt + 1 < NT){
      #pragma unroll
      for (int i=0;i<4;i++){
        ra[i] = ld4(Ag + (kt+1)*64 + i*4);
        rb[i] = ld4(Bg + (kt+1)*64 + i*4);
      }
    }
    #pragma unroll
    for (int ks = 0; ks < 64; ks += 32){
      const int ko = ks + fq*8;
      s16x8 aH0 = *(const s16x8*)&AsH[aB0 + ko];
      s16x8 aH1 = *(const s16x8*)&AsH[aB1 + ko];
      s16x8 aL0 = *(const s16x8*)&AsL[aB0 + ko];
      s16x8 aL1 = *(const s16x8*)&AsL[aB1 + ko];
      s16x8 bH0 = *(const s16x8*)&BsH[bB0 + ko];
      s16x8 bH1 = *(const s16x8*)&BsH[bB1 + ko];
      s16x8 bL0 = *(const s16x8*)&BsL[bB0 + ko];
      s16x8 bL1 = *(const s16x8*)&BsL[bB1 + ko];
      acc00 = MFMA(aH0,bH0,acc00); acc00 = MFMA(aH0,bL0,acc00); acc00 = MFMA(aL0,bH0,acc00);
      acc01 = MFMA(aH0,bH1,acc01); acc01 = MFMA(aH0,bL1,acc01); acc01 = MFMA(aL0,bH1,acc01);
      acc10 = MFMA(aH1,bH0,acc10); acc10 = MFMA(aH1,bL0,acc10); acc10 = MFMA(aL1,bH0,acc10);
      acc11 = MFMA(aH1,bH1,acc11); acc11 = MFMA(aH1,bL1,acc11); acc11 = MFMA(aL1,bH1,acc11);
    }
    __syncthreads();
  }

  float* Yt = (float*)smem;    // [64][72]
  #pragma unroll
  for (int i=0;i<4;i++){
    Yt[(nq      + fr)*72 + mq      + fq*4 + i] = acc00[i];
    Yt[(nq + 16 + fr)*72 + mq      + fq*4 + i] = acc01[i];
    Yt[(nq      + fr)*72 + mq + 16 + fq*4 + i] = acc10[i];
    Yt[(nq + 16 + fr)*72 + mq + 16 + fq*4 + i] = acc11[i];
  }
  __syncthreads();
  #pragma unroll
  for (int i=0;i<4;i++){
    float4 r = *(float4*)&Yt[sr*72 + scB + i*4];
    if (EPI == 1) r = f4sqrelu(r);
    float* dst = &Y[(size_t)(n0 + sr)*M + m0 + scB + i*4];
    if (ACC) r = f4add(r, ld4(dst));
    st4(dst, r);
  }
}

// ---------------- channel mix (dw) ----------------
template<int MODE>
__global__ __launch_bounds__(256) void dwmix_k(
    const float* __restrict__ T, const float* __restrict__ dwp,
    const float* __restrict__ Z, float* __restrict__ O, int F)
{
  int idx = blockIdx.x*256 + threadIdx.x;
  int perb = F << 7;
  int b = idx / perb; int rem = idx - b*perb;
  size_t i0 = ((size_t)(b*2) * F)*512 + (size_t)rem*4;
  size_t i1 = i0 + (size_t)F*512;
  float4 t0 = ld4(T + i0), t1 = ld4(T + i1);
  float d00 = dwp[0], d01 = dwp[1], d10 = dwp[2], d11 = dwp[3];
  float4 o0 = f4fma2(d00, t0, d01, t1);
  float4 o1 = f4fma2(d10, t0, d11, t1);
  if (MODE == 1){ o0 = f4sqrelu(o0); o1 = f4sqrelu(o1); }
  if (MODE == 2){ o0 = f4add(o0, ld4(Z + i0)); o1 = f4add(o1, ld4(Z + i1)); }
  st4(O + i0, o0);
  st4(O + i1, o1);
}

// ---------------- fused qkv post: dw-mix (+rope for q,k), wf layout ----------------
__global__ __launch_bounds__(256) void qkv_post_k(
    const float* __restrict__ QY, const float* __restrict__ qdw,
    const float* __restrict__ kdw, const float* __restrict__ vdw,
    float* __restrict__ qB, float* __restrict__ kB, float* __restrict__ vB,
    const float* __restrict__ cosT, const float* __restrict__ sinT)
{
  int p = blockIdx.y;
  const float* T = QY + (size_t)p*1048576;
  const float* dwp = (p==0) ? qdw : ((p==1) ? kdw : vdw);
  float* O = (p==0) ? qB : ((p==1) ? kB : vB);
  int idx = blockIdx.x*256 + threadIdx.x;
  int b = idx >> 16; int rem = idx & 65535;
  int w = rem >> 7; int f = (rem & 127) << 2;
  size_t i0 = ((size_t)(b*2)*512 + w)*512 + f;
  size_t i1 = i0 + 262144;
  float4 t0 = ld4(T+i0), t1 = ld4(T+i1);
  float d00 = dwp[0], d01 = dwp[1], d10 = dwp[2], d11 = dwp[3];
  float4 o0 = f4fma2(d00, t0, d01, t1);
  float4 o1 = f4fma2(d10, t0, d11, t1);
  if (p < 2){
    int j = (f & 63) >> 1;
    float c0 = cosT[w*32 + j], c1 = cosT[w*32 + j + 1];
    float s0 = sinT[w*32 + j], s1 = sinT[w*32 + j + 1];
    float4 r0, r1;
    r0.x = o0.x*c0 - o0.y*s0;  r0.y = o0.y*c0 + o0.x*s0;
    r0.z = o0.z*c1 - o0.w*s1;  r0.w = o0.w*c1 + o0.z*s1;
    r1.x = o1.x*c0 - o1.y*s0;  r1.y = o1.y*c0 + o1.x*s0;
    r1.z = o1.z*c1 - o1.w*s1;  r1.w = o1.w*c1 + o1.z*s1;
    o0 = r0; o1 = r1;
  }
  st4(O + i0, o0);
  st4(O + i1, o1);
}

// ---------------- transpose x: [bc][1024 f][512 w] -> [bc][512 w][1024 f] ----------------
__global__ __launch_bounds__(256) void transpose_x_k(const float* __restrict__ X, float* __restrict__ XT){
  __shared__ float T[64][68];
  int w0 = blockIdx.x << 6, f0 = blockIdx.y << 6, bc = blockIdx.z;
  int r = threadIdx.x >> 2, c4 = (threadIdx.x & 3) << 4;
  const float* src = X + ((size_t)bc*1024 + f0 + r)*512 + w0 + c4;
  #pragma unroll
  for (int i=0;i<4;i++) st4(&T[r][c4 + i*4], ld4(src + i*4));
  __syncthreads();
  float* dst = XT + ((size_t)bc*512 + w0 + r)*1024 + f0 + c4;
  #pragma unroll
  for (int i=0;i<4;i++){
    float4 v;
    v.x = T[c4+i*4+0][r]; v.y = T[c4+i*4+1][r]; v.z = T[c4+i*4+2][r]; v.w = T[c4+i*4+3][r];
    st4(dst + i*4, v);
  }
}

// ---------------- final: dw-mix + add Z, transpose wf -> (b,c,1024,512) ----------------
__global__ __launch_bounds__(256) void out_t_k(const float* __restrict__ T_, const float* __restrict__ dwp,
                                               const float* __restrict__ Z, float* __restrict__ O){
  __shared__ float T0[64][68], T1[64][68];
  int w0 = blockIdx.x << 6, f0 = blockIdx.y << 6, b = blockIdx.z;
  int r = threadIdx.x >> 2, c4 = (threadIdx.x & 3) << 4;
  size_t base0 = ((size_t)(b*2)*512 + w0 + r)*1024 + f0 + c4;
  size_t base1 = base0 + 524288;
  float d00 = dwp[0], d01 = dwp[1], d10 = dwp[2], d11 = dwp[3];
  #pragma unroll
  for (int i=0;i<4;i++){
    float4 t0 = ld4(T_+base0+i*4), t1 = ld4(T_+base1+i*4);
    float4 z0 = ld4(Z+base0+i*4),  z1 = ld4(Z+base1+i*4);
    st4(&T0[r][c4+i*4], f4add(f4fma2(d00,t0,d01,t1), z0));
    st4(&T1[r][c4+i*4], f4add(f4fma2(d10,t0,d11,t1), z1));
  }
  __syncthreads();
  size_t ob0 = ((size_t)(b*2)*1024 + f0 + r)*512 + w0 + c4;
  size_t ob1 = ob0 + 524288;
  #pragma unroll
  for (int i=0;i<4;i++){
    float4 v0, v1;
    v0.x=T0[c4+i*4+0][r]; v0.y=T0[c4+i*4+1][r]; v0.z=T0[c4+i*4+2][r]; v0.w=T0[c4+i*4+3][r];
    v1.x=T1[c4+i*4+0][r]; v1.y=T1[c4+i*4+1][r]; v1.z=T1[c4+i*4+2][r]; v1.w=T1[c4+i*4+3][r];
    st4(O+ob0+i*4, v0);
    st4(O+ob1+i*4, v1);
  }
}

// ---------------- MFMA fused attention, wf layout ----------------
// grid (8 q-tiles, 8 heads, 4 bc); block 256 = 4 waves; k-tile = 64.
// QK^T and PV via split-bf16 MFMA (3-term); softmax fp32 on LDS S-tile.
// Wave wv owns q rows [wv*16, wv*16+16).
__global__ __launch_bounds__(256) void attn_k(
    const float* __restrict__ Q, const float* __restrict__ K,
    const float* __restrict__ V, float* __restrict__ O)
{
  const int q0 = blockIdx.x << 6;
  const int hc = blockIdx.y << 6;
  const int bc = blockIdx.z;
  const size_t cb = (size_t)bc*262144;
  const float* Qp = Q + cb;
  const float* Kp = K + cb;
  const float* Vp = V + cb;
  float*       Op = O + cb;

  __shared__ __align__(16) unsigned short QH[64*72];   // Q [q][d]
  __shared__ __align__(16) unsigned short QL[64*72];
  __shared__ __align__(16) unsigned short TH[64*72];   // K tile [k'][d], then V^T [d][k']
  __shared__ __align__(16) unsigned short TL[64*72];
  __shared__ float St[64*68];                           // [q][k'] scores / probs / out staging
  __shared__ float mL[64], lL[64], aL[64];

  const int t = threadIdx.x, lane = t & 63, wv = t >> 6;
  const int fr = lane & 15, fq = lane >> 4;
  const int mq = wv << 4;

  // stage Q tile once
  {
    int r = t >> 2, c16 = (t & 3) << 4;
    const float* src = Qp + (size_t)(q0 + r)*512 + hc + c16;
    float4 v0 = ld4(src), v1 = ld4(src+4), v2 = ld4(src+8), v3 = ld4(src+12);
    s16x8 h,l;
    cvt8(v0,v1,&h,&l); *(s16x8*)&QH[r*72+c16]   = h; *(s16x8*)&QL[r*72+c16]   = l;
    cvt8(v2,v3,&h,&l); *(s16x8*)&QH[r*72+c16+8] = h; *(s16x8*)&QL[r*72+c16+8] = l;
  }
  if (t < 64){ mL[t] = -1e30f; lL[t] = 0.f; }

  f32x4 oA[4] = {{0,0,0,0},{0,0,0,0},{0,0,0,0},{0,0,0,0}};
  const float sc = 0.044194173824159216f;   // 1/sqrt(512) (=F, per reference)

  for (int k0 = 0; k0 < 512; k0 += 64){
    __syncthreads();                     // prev PV done with TH/TL and St
    // stage K tile [k'][d]
    {
      int r = t >> 2, c16 = (t & 3) << 4;
      const float* src = Kp + (size_t)(k0 + r)*512 + hc + c16;
      float4 v0 = ld4(src), v1 = ld4(src+4), v2 = ld4(src+8), v3 = ld4(src+12);
      s16x8 h,l;
      cvt8(v0,v1,&h,&l); *(s16x8*)&TH[r*72+c16]   = h; *(s16x8*)&TL[r*72+c16]   = l;
      cvt8(v2,v3,&h,&l); *(s16x8*)&TH[r*72+c16+8] = h; *(s16x8*)&TL[r*72+c16+8] = l;
    }
    __syncthreads();
    // S = Q K^T (3-term split), write to St
    {
      f32x4 sA[4] = {{0,0,0,0},{0,0,0,0},{0,0,0,0},{0,0,0,0}};
      #pragma unroll
      for (int ks = 0; ks < 64; ks += 32){
        int ao = (mq + fr)*72 + ks + fq*8;
        s16x8 aH = *(const s16x8*)&QH[ao];
        s16x8 aLo = *(const s16x8*)&QL[ao];
        #pragma unroll
        for (int nt = 0; nt < 4; nt++){
          int bo = ((nt<<4) + fr)*72 + ks + fq*8;
          s16x8 bH = *(const s16x8*)&TH[bo];
          s16x8 bLo = *(const s16x8*)&TL[bo];
          sA[nt] = MFMA(aH,bH,sA[nt]);
          sA[nt] = MFMA(aLo,bH,sA[nt]);
          sA[nt] = MFMA(aH,bLo,sA[nt]);
        }
      }
      #pragma unroll
      for (int nt = 0; nt < 4; nt++)
        #pragma unroll
        for (int i = 0; i < 4; i++)
          St[(mq + fq*4 + i)*68 + (nt<<4) + fr] = sA[nt][i]*sc;
    }
    __syncthreads();
    // online softmax (fp32) — 4 threads per q-row, 16 cols each
    {
      int r = t >> 2, sub = t & 3;
      float* row = &St[r*68 + (sub << 4)];
      float4 x0 = ((float4*)row)[0], x1 = ((float4*)row)[1];
      float4 x2 = ((float4*)row)[2], x3 = ((float4*)row)[3];
      float mx = fmaxf(fmaxf(fmaxf(x0.x,x0.y),fmaxf(x0.z,x0.w)),
                       fmaxf(fmaxf(x1.x,x1.y),fmaxf(x1.z,x1.w)));
      mx = fmaxf(mx, fmaxf(fmaxf(fmaxf(x2.x,x2.y),fmaxf(x2.z,x2.w)),
                           fmaxf(fmaxf(x3.x,x3.y),fmaxf(x3.z,x3.w))));
      mx = fmaxf(mx, __shfl_xor(mx, 1));
      mx = fmaxf(mx, __shfl_xor(mx, 2));
      float mo = mL[r];
      float mn = fmaxf(mo, mx);
      float al = __expf(mo - mn);
      x0.x=__expf(x0.x-mn); x0.y=__expf(x0.y-mn); x0.z=__expf(x0.z-mn); x0.w=__expf(x0.w-mn);
      x1.x=__expf(x1.x-mn); x1.y=__expf(x1.y-mn); x1.z=__expf(x1.z-mn); x1.w=__expf(x1.w-mn);
      x2.x=__expf(x2.x-mn); x2.y=__expf(x2.y-mn); x2.z=__expf(x2.z-mn); x2.w=__expf(x2.w-mn);
      x3.x=__expf(x3.x-mn); x3.y=__expf(x3.y-mn); x3.z=__expf(x3.z-mn); x3.w=__expf(x3.w-mn);
      float sm = (x0.x+x0.y+x0.z+x0.w) + (x1.x+x1.y+x1.z+x1.w)
               + (x2.x+x2.y+x2.z+x2.w) + (x3.x+x3.y+x3.z+x3.w);
      sm += __shfl_xor(sm, 1);
      sm += __shfl_xor(sm, 2);
      ((float4*)row)[0]=x0; ((float4*)row)[1]=x1; ((float4*)row)[2]=x2; ((float4*)row)[3]=x3;
      if (sub == 0){ mL[r] = mn; lL[r] = lL[r]*al + sm; aL[r] = al; }
    }
    // stage V transposed into TH/TL: V^T[d][k'], lane = k' (conflict-free stores)
    {
      int c16 = wv << 4;
      const float* src = Vp + (size_t)(k0 + lane)*512 + hc + c16;
      #pragma unroll
      for (int jj = 0; jj < 16; jj += 4){
        float4 v = ld4(src + jj);
        float f[4] = {v.x, v.y, v.z, v.w};
        #pragma unroll
        for (int e = 0; e < 4; e++){
          unsigned u = __float_as_uint(f[e]);
          TH[(c16+jj+e)*72 + lane] = (unsigned short)(u>>16);
          float hf = __uint_as_float(u & 0xffff0000u);
          TL[(c16+jj+e)*72 + lane] = (unsigned short)(__float_as_uint(f[e]-hf)>>16);
        }
      }
    }
    __syncthreads();
    // rescale O by alpha, then O += P V (3-term split)
    {
      float a0 = aL[mq + fq*4 + 0], a1 = aL[mq + fq*4 + 1];
      float a2 = aL[mq + fq*4 + 2], a3 = aL[mq + fq*4 + 3];
      #pragma unroll
      for (int nt = 0; nt < 4; nt++){
        oA[nt][0] *= a0; oA[nt][1] *= a1; oA[nt][2] *= a2; oA[nt][3] *= a3;
      }
      #pragma unroll
      for (int ks = 0; ks < 64; ks += 32){
        const float* pr = &St[(mq + fr)*68 + ks + fq*8];
        float4 p0 = ld4(pr), p1 = ld4(pr+4);
        s16x8 pH, pL;
        cvt8(p0, p1, &pH, &pL);
        #pragma unroll
        for (int nt = 0; nt < 4; nt++){
          int bo = ((nt<<4) + fr)*72 + ks + fq*8;
          s16x8 bH = *(const s16x8*)&TH[bo];
          s16x8 bLo = *(const s16x8*)&TL[bo];
          oA[nt] = MFMA(pH,bH,oA[nt]);
          oA[nt] = MFMA(pL,bH,oA[nt]);
          oA[nt] = MFMA(pH,bLo,oA[nt]);
        }
      }
    }
  }
  // normalize and stage O into St [q][d], then coalesced write
  {
    float i0 = 1.f / lL[mq + fq*4 + 0], i1 = 1.f / lL[mq + fq*4 + 1];
    float i2 = 1.f / lL[mq + fq*4 + 2], i3 = 1.f / lL[mq + fq*4 + 3];
    #pragma unroll
    for (int nt = 0; nt < 4; nt++){
      St[(mq + fq*4 + 0)*68 + (nt<<4) + fr] = oA[nt][0]*i0;
      St[(mq + fq*4 + 1)*68 + (nt<<4) + fr] = oA[nt][1]*i1;
      St[(mq + fq*4 + 2)*68 + (nt<<4) + fr] = oA[nt][2]*i2;
      St[(mq + fq*4 + 3)*68 + (nt<<4) + fr] = oA[nt][3]*i3;
    }
  }
  __syncthreads();
  {
    int r = t >> 2, c16 = (t & 3) << 4;
    float* dst = Op + (size_t)(q0 + r)*512 + hc + c16;
    #pragma unroll
    for (int i = 0; i < 4; i++) st4(dst + i*4, *(float4*)&St[r*68 + c16 + i*4]);
  }
}

extern "C" void kernel_launch(void* const* d_in, const int* in_sizes, int n_in,
                              void* d_out, int out_size, void* d_ws, size_t ws_size,
                              hipStream_t stream) {
  (void)in_sizes; (void)n_in; (void)out_size; (void)ws_size;
  const float* x     = (const float*)d_in[0];
  const float* e1_pw = (const float*)d_in[1];
  const float* e1_dw = (const float*)d_in[2];
  const float* e2_pw = (const float*)d_in[3];
  const float* e2_dw = (const float*)d_in[4];
  const float* ei_pw = (const float*)d_in[5];
  const float* ei_dw = (const float*)d_in[6];
  const float* n1_w  = (const float*)d_in[7];
  const float* n1_b  = (const float*)d_in[8];
  const float* q_pw  = (const float*)d_in[9];
  const float* q_dw  = (const float*)d_in[10];
  const float* k_pw  = (const float*)d_in[11];
  const float* k_dw  = (const float*)d_in[12];
  const float* v_pw  = (const float*)d_in[13];
  const float* v_dw  = (const float*)d_in[14];
  const float* o_pw  = (const float*)d_in[15];
  const float* n2_w  = (const float*)d_in[16];
  const float* n2_b  = (const float*)d_in[17];
  const float* f1_pw = (const float*)d_in[18];
  const float* f2_pw = (const float*)d_in[19];
  const float* d1_pw = (const float*)d_in[20];
  const float* d1_dw = (const float*)d_in[21];
  const float* d2_pw = (const float*)d_in[22];
  const float* d2_dw = (const float*)d_in[23];
  const float* di_pw = (const float*)d_in[24];
  const float* di_dw = (const float*)d_in[25];

  float* W    = (float*)d_ws;
  float* bufA = W;                       // 3M
  float* eB   = W + 3145728;             // 1M
  float* R    = W + 4194304;             // 4M pool
  float* qB   = R;
  float* kB   = R + 1048576;
  float* vB   = R + 2097152;
  float* pool = R;
  float* xT   = R;
  float* MU   = W + 8388608;
  float* RS   = MU + 2048;
  float* cosT = RS + 2048;
  float* sinT = cosT + 16384;
  float* os   = (float*)d_out;

  const float* NP = nullptr;
  const dim3 blk(256);

  rope_tab_k<<<64, blk, 0, stream>>>(cosT, sinT);
  transpose_x_k<<<dim3(8,16,4), blk, 0, stream>>>(x, xT);

  // ---- encoder frame_block ----
  mm_k<0,false,false,false><<<dim3(8,8,4), blk, 0, stream>>>(e1_pw,NP,NP, xT, bufA, 512, 1024, NP,NP,NP,NP);
  dwmix_k<1><<<512, blk, 0, stream>>>(bufA, e1_dw, NP, R + 2097152, 512);
  mm_k<0,false,false,false><<<dim3(8,8,4), blk, 0, stream>>>(e2_pw,NP,NP, R + 2097152, bufA, 512, 512, NP,NP,NP,NP);
  dwmix_k<0><<<512, blk, 0, stream>>>(bufA, e2_dw, NP, R + 3145728, 512);
  mm_k<0,false,false,false><<<dim3(8,8,4), blk, 0, stream>>>(ei_pw,NP,NP, xT, bufA, 512, 1024, NP,NP,NP,NP);
  dwmix_k<2><<<512, blk, 0, stream>>>(bufA, ei_dw, R + 3145728, eB, 512);

  // ---- 12 layers ----
  for (int i = 0; i < 12; i++){
    const float* n1w = n1_w + i*1024; const float* n1b = n1_b + i*1024;
    const float* n2w = n2_w + i*1024; const float* n2b = n2_b + i*1024;
    size_t qo = (size_t)i*524288, fo = (size_t)i*2097152;

    stats_k<<<512, blk, 0, stream>>>(eB, MU, RS);
    mm_k<0,false,true,true><<<dim3(8,8,12), blk, 0, stream>>>(q_pw+qo, k_pw+qo, v_pw+qo, eB, bufA, 512, 512, MU, RS, n1w, n1b);
    qkv_post_k<<<dim3(512,3), blk, 0, stream>>>(bufA, q_dw+i*4, k_dw+i*4, v_dw+i*4, qB, kB, vB, cosT, sinT);
    attn_k<<<dim3(8,8,4), blk, 0, stream>>>(qB, kB, vB, bufA);
    mm_k<0,true,false,false><<<dim3(8,8,4), blk, 0, stream>>>(o_pw+qo,NP,NP, bufA, eB, 512, 512, NP,NP,NP,NP);

    stats_k<<<512, blk, 0, stream>>>(eB, MU, RS);
    mm_k<1,false,true,false><<<dim3(8,32,4), blk, 0, stream>>>(f1_pw+fo,NP,NP, eB, pool, 2048, 512, MU, RS, n2w, n2b);
    mm_k<0,true,false,false><<<dim3(8,8,4), blk, 0, stream>>>(f2_pw+fo,NP,NP, pool, eB, 512, 2048, NP,NP,NP,NP);
  }

  // ---- decoder frame_block ----
  mm_k<0,false,false,false><<<dim3(8,16,4), blk, 0, stream>>>(d1_pw,NP,NP, eB, bufA, 1024, 512, NP,NP,NP,NP);
  dwmix_k<1><<<1024, blk, 0, stream>>>(bufA, d1_dw, NP, R + 2097152, 1024);
  mm_k<0,false,false,false><<<dim3(8,16,4), blk, 0, stream>>>(d2_pw,NP,NP, R + 2097152, bufA, 1024, 1024, NP,NP,NP,NP);
  dwmix_k<0><<<1024, blk, 0, stream>>>(bufA, d2_dw, NP, R, 1024);
  mm_k<0,false,false,false><<<dim3(8,16,4), blk, 0, stream>>>(di_pw,NP,NP, eB, bufA, 1024, 512, NP,NP,NP,NP);
  out_t_k<<<dim3(8,16,2), blk, 0, stream>>>(bufA, di_dw, R, os);
}